// Round 7
// baseline (654.397 us; speedup 1.0000x reference)
//
#include <hip/hip_runtime.h>
#include <hip/hip_cooperative_groups.h>
#include <cstdint>

namespace cg = cooperative_groups;

#define B 32
#define D 8732
#define C 21
#define L 32
#define O 8
#define NS 8
#define SLICE 1092     // ceil(D/8)
#define GRID 256       // B*NS
#define NT 1024

struct Params {
  const float *loc, *conf, *line, *pose, *dbox, *targets;
  float* out;
  unsigned long long* bp;   // 256
  int* cnt;                 // 256 (per b,slice positive count, uncapped)
  int* posSlice;            // 256*256 packed (d | cls<<14 | bi<<19)
  float* sce;               // B*D mined-ce
  double* gLossL; double* gLossP; double* gCeP;   // 256 per-block partials
  double* gCeNeg;           // 32
  double* gDesk; double* gNpp; double* gNnp; double* gTripS; double* gTripC; // 256
  int* gPc;                 // 1
  float* emb; float* nemb; float* qp; int* lab;   // 256-row gathered
};

__device__ inline double waveSumD(double v) {
  #pragma unroll
  for (int s = 32; s > 0; s >>= 1) v += __shfl_down(v, s, 64);
  return v;
}

__device__ inline float iou_one(float tx1, float ty1, float tx2, float ty2, float ta,
                                float px1, float py1, float px2, float py2, float areaB) {
  float lx = fmaxf(tx1, px1), ly = fmaxf(ty1, py1);
  float rx = fminf(tx2, px2), ry = fminf(ty2, py2);
  float iw = fmaxf(rx - lx, 0.f), ih = fmaxf(ry - ly, 0.f);
  float inter = iw * ih;
  return inter / (ta + areaB - inter);
}

union SharedU {
  struct {                       // P0/P1/P2
    float tb[O][4], ta[O], tl[O], tp[O][3];
    int bpd[O];
    unsigned long long wm[16][O];
    int plist[256];
    int wcnt[16], wbase[16];
    double wred[16][3];
    int run;
  } a;
  struct {                       // P3 radix + gather
    __align__(16) float sce[D];
    int whist[16][256];
    int hist[256];
    int sc[256];
    int p8[NS + 1];
    int gb;
    unsigned prefixSh; int kkSh;
    double wsum[16], wcnt2[16];
  } r;
  struct {                       // P4 pairs+trip
    float ei[L], ni[L], qi[3];
    float sd[256];
    unsigned long long spm[4], snm[4];
    double w1[4];
    int ppc[4], npc[4];
    double wS[16], wC[16];
    int li, pc;
  } q;
  struct {                       // P5 reduce
    double lbuf[16];
  } f;
};

__device__ inline double blockSumD(const double* a, int n, double* lbuf, int tid) {
  double v = 0;
  for (int i = tid; i < n; i += NT) v += a[i];
  v = waveSumD(v);
  __syncthreads();
  if ((tid & 63) == 0) lbuf[tid >> 6] = v;
  __syncthreads();
  double r = 0;
  #pragma unroll
  for (int w = 0; w < 16; w++) r += lbuf[w];
  return r;
}

__device__ inline double blockSumI(const int* a, int n, double* lbuf, int tid) {
  double v = 0;
  for (int i = tid; i < n; i += NT) v += (double)a[i];
  v = waveSumD(v);
  __syncthreads();
  if ((tid & 63) == 0) lbuf[tid >> 6] = v;
  __syncthreads();
  double r = 0;
  #pragma unroll
  for (int w = 0; w < 16; w++) r += lbuf[w];
  return r;
}

__global__ __launch_bounds__(NT) void k_mega(Params p) {
  cg::grid_group gg = cg::this_grid();
  __shared__ SharedU sh;
  int g = blockIdx.x, tid = threadIdx.x;
  int lane = tid & 63, wav = tid >> 6;
  const unsigned long long lt = (lane == 0) ? 0ull : (~0ull >> (64 - lane));
  int b = g >> 3, s = g & 7;
  int dBeg = s * SLICE;
  int dEnd = dBeg + SLICE; if (dEnd > D) dEnd = D;

  // ---- P0: zero bp, load truths ----
  if (tid == 0) p.bp[g] = 0ull;
  if (tid < O) {
    const float* tr = p.targets + ((size_t)b * O + tid) * 9;
    sh.a.tb[tid][0] = tr[0]; sh.a.tb[tid][1] = tr[1];
    sh.a.tb[tid][2] = tr[2]; sh.a.tb[tid][3] = tr[3];
    sh.a.ta[tid] = (tr[2] - tr[0]) * (tr[3] - tr[1]);
    sh.a.tl[tid] = tr[4];
    sh.a.tp[tid][0] = tr[5]; sh.a.tp[tid][1] = tr[6]; sh.a.tp[tid][2] = tr[7];
  }
  __syncthreads();
  __threadfence();
  gg.sync();                                   // S1: bp zeroed everywhere

  // ---- P1: per-truth best prior over this slice -> atomicMax ----
  {
    unsigned long long key[O];
    #pragma unroll
    for (int t = 0; t < O; t++) key[t] = 0ull;
    for (int d = dBeg + tid; d < dEnd; d += NT) {
      float4 db = *(const float4*)(p.dbox + (size_t)d * 4);
      float px1 = db.x - 0.5f*db.z, py1 = db.y - 0.5f*db.w;
      float px2 = db.x + 0.5f*db.z, py2 = db.y + 0.5f*db.w;
      float areaB = db.z * db.w;
      #pragma unroll
      for (int t = 0; t < O; t++) {
        float iou = iou_one(sh.a.tb[t][0], sh.a.tb[t][1], sh.a.tb[t][2], sh.a.tb[t][3],
                            sh.a.ta[t], px1, py1, px2, py2, areaB);
        unsigned long long kk = ((unsigned long long)__float_as_uint(iou) << 32)
                              | (unsigned long long)(0xFFFFFFFFu - (unsigned)d);
        if (kk > key[t]) key[t] = kk;
      }
    }
    #pragma unroll
    for (int t = 0; t < O; t++) {
      unsigned long long k = key[t];
      #pragma unroll
      for (int sft = 32; sft > 0; sft >>= 1) {
        unsigned long long o = __shfl_down(k, sft, 64);
        if (o > k) k = o;
      }
      if (lane == 0) sh.a.wm[wav][t] = k;
    }
    __syncthreads();
    if (tid < O) {
      unsigned long long k = sh.a.wm[0][tid];
      #pragma unroll
      for (int w = 1; w < 16; w++) if (sh.a.wm[w][tid] > k) k = sh.a.wm[w][tid];
      atomicMax(&p.bp[b * O + tid], k);
    }
  }
  __threadfence();
  gg.sync();                                   // S2: bp final

  if (tid < O) {
    unsigned long long k = p.bp[b * O + tid];
    sh.a.bpd[tid] = (int)(0xFFFFFFFFu - (unsigned)(k & 0xFFFFFFFFull));
  }
  if (tid == 0) sh.a.run = 0;
  __syncthreads();

  // ---- P2: match, CE, loc/pose losses, compaction over this slice ----
  {
    double ll = 0, lp = 0, cp = 0;
    for (int d0 = dBeg; d0 < dEnd; d0 += NT) {
      int d = d0 + tid;
      bool act = d < dEnd;
      int cls = 0, bi = 0;
      if (act) {
        float4 db = *(const float4*)(p.dbox + (size_t)d * 4);
        float px1 = db.x - 0.5f*db.z, py1 = db.y - 0.5f*db.w;
        float px2 = db.x + 0.5f*db.z, py2 = db.y + 0.5f*db.w;
        float areaB = db.z * db.w;
        float bv = -1.0f;
        #pragma unroll
        for (int t = 0; t < O; t++) {
          float iou = iou_one(sh.a.tb[t][0], sh.a.tb[t][1], sh.a.tb[t][2], sh.a.tb[t][3],
                              sh.a.ta[t], px1, py1, px2, py2, areaB);
          if (iou > bv) { bv = iou; bi = t; }     // argmax axis=0: first max wins
        }
        #pragma unroll
        for (int t = O - 1; t >= 0; t--)          // numpy scatter: last truth wins
          if (sh.a.bpd[t] == d) { bi = t; bv = 2.0f; break; }
        cls = (bv < 0.5f) ? 0 : ((int)sh.a.tl[bi] + 1);
        const float* cb = p.conf + ((size_t)b * D + d) * C;
        float x[C];
        #pragma unroll
        for (int c = 0; c < C; c++) x[c] = cb[c];
        float m = x[0];
        #pragma unroll
        for (int c = 1; c < C; c++) m = fmaxf(m, x[c]);
        float sm = 0.f;
        #pragma unroll
        for (int c = 0; c < C; c++) sm += __expf(x[c] - m);
        float xc = x[0];
        #pragma unroll
        for (int c = 1; c < C; c++) xc = (cls == c) ? x[c] : xc;
        float ce = m + __logf(sm) - xc;
        size_t bd = (size_t)b * D + d;
        if (cls > 0) {
          cp += ce;
          p.sce[bd] = 0.f;
          float g0 = ((sh.a.tb[bi][0] + sh.a.tb[bi][2]) * 0.5f - db.x) / (0.1f * db.z);
          float g1 = ((sh.a.tb[bi][1] + sh.a.tb[bi][3]) * 0.5f - db.y) / (0.1f * db.w);
          float g2 = logf((sh.a.tb[bi][2] - sh.a.tb[bi][0]) / db.z) / 0.2f;
          float g3 = logf((sh.a.tb[bi][3] - sh.a.tb[bi][1]) / db.w) / 0.2f;
          float4 lo = *(const float4*)(p.loc + bd * 4);
          float dv, a;
          dv = lo.x - g0; a = fabsf(dv); ll += (double)((a < 1.f) ? 0.5f*dv*dv : a - 0.5f);
          dv = lo.y - g1; a = fabsf(dv); ll += (double)((a < 1.f) ? 0.5f*dv*dv : a - 0.5f);
          dv = lo.z - g2; a = fabsf(dv); ll += (double)((a < 1.f) ? 0.5f*dv*dv : a - 0.5f);
          dv = lo.w - g3; a = fabsf(dv); ll += (double)((a < 1.f) ? 0.5f*dv*dv : a - 0.5f);
          const float* po = p.pose + bd * 3;
          #pragma unroll
          for (int q = 0; q < 3; q++) {
            float pd = po[q] - sh.a.tp[bi][q];
            lp += (double)pd * (double)pd;
          }
        } else {
          p.sce[bd] = fmaxf(ce, 0.f);
        }
      }
      bool pos = act && (cls > 0);
      unsigned long long mm = __ballot(pos);
      if (lane == 0) sh.a.wcnt[wav] = __popcll(mm);
      __syncthreads();
      if (tid == 0) {
        int r = sh.a.run;
        #pragma unroll
        for (int w = 0; w < 16; w++) { sh.a.wbase[w] = r; r += sh.a.wcnt[w]; }
        sh.a.run = r;
      }
      __syncthreads();
      if (pos) {
        int rank = sh.a.wbase[wav] + __popcll(mm & lt);
        if (rank < 256) sh.a.plist[rank] = d | (cls << 14) | (bi << 19);
      }
      __syncthreads();
    }
    int tot = sh.a.run;
    if (tid == 0) p.cnt[g] = tot;
    int stored = (tot < 256) ? tot : 256;
    if (tid < stored) p.posSlice[g * 256 + tid] = sh.a.plist[tid];
    double a0 = waveSumD(ll), a1 = waveSumD(lp), a2 = waveSumD(cp);
    if (lane == 0) { sh.a.wred[wav][0] = a0; sh.a.wred[wav][1] = a1; sh.a.wred[wav][2] = a2; }
    __syncthreads();
    if (tid == 0) {
      double tll = 0, tlp = 0, tcp = 0;
      #pragma unroll
      for (int w = 0; w < 16; w++) { tll += sh.a.wred[w][0]; tlp += sh.a.wred[w][1]; tcp += sh.a.wred[w][2]; }
      p.gLossL[g] = tll; p.gLossP[g] = tlp; p.gCeP[g] = tcp;
    }
  }
  __threadfence();
  gg.sync();                                   // S3: sce/cnt/posSlice ready

  // ---- P3: per-batch (32 blocks): gather positives + radix top-k ----
  if (g < B) {
    int bb = g;
    if (tid < 256) sh.r.sc[tid] = p.cnt[tid];
    __syncthreads();
    if (tid == 0) {
      int gb = 0;
      for (int i = 0; i < bb * NS; i++) gb += sh.r.sc[i];
      sh.r.gb = gb;
      int run = 0;
      for (int ss = 0; ss < NS; ss++) { sh.r.p8[ss] = run; run += sh.r.sc[bb * NS + ss]; }
      sh.r.p8[NS] = run;                          // npos of this batch
      if (bb == 0) {
        int totAll = 0;
        for (int i = 0; i < 256; i++) totAll += sh.r.sc[i];
        *p.gPc = (totAll < 256) ? totAll : 256;
      }
    }
    __syncthreads();
    int gb = sh.r.gb, npos = sh.r.p8[NS];
    int nr = (npos < 256) ? npos : 256;
    if (tid < nr) {
      int r = tid, ss = 0;
      #pragma unroll
      for (int q = 1; q < NS; q++) if (r >= sh.r.p8[q]) ss = q;
      int idx = r - sh.r.p8[ss];
      int slot = gb + r;
      if (idx < 256 && slot < 256) {
        int packed = p.posSlice[(bb * NS + ss) * 256 + idx];
        int d   = packed & 0x3FFF;
        int cls = (packed >> 14) & 31;
        int bi  = (packed >> 19) & 7;
        size_t flat = (size_t)bb * D + d;
        const float4* e4 = (const float4*)(p.line + flat * L);
        float4* o4 = (float4*)(p.emb + slot * L);
        float4* n4 = (float4*)(p.nemb + slot * L);
        float4 v[8];
        float nrm2 = 0.f;
        #pragma unroll
        for (int c = 0; c < 8; c++) {
          v[c] = e4[c];
          o4[c] = v[c];
          nrm2 += v[c].x*v[c].x + v[c].y*v[c].y + v[c].z*v[c].z + v[c].w*v[c].w;
        }
        float inv = 1.f / fmaxf(sqrtf(nrm2), 1e-12f);
        #pragma unroll
        for (int c = 0; c < 8; c++) {
          float4 t = v[c];
          t.x *= inv; t.y *= inv; t.z *= inv; t.w *= inv;
          n4[c] = t;
        }
        p.lab[slot] = cls;
        const float* tr = p.targets + ((size_t)bb * O + bi) * 9;
        p.qp[slot * 3 + 0] = tr[5]; p.qp[slot * 3 + 1] = tr[6]; p.qp[slot * 3 + 2] = tr[7];
      }
    }
    // radix top-k over this batch's mined ce (k = 3*npos)
    const float* ce = p.sce + (size_t)bb * D;
    for (int i = tid; i < D / 4; i += NT)
      ((float4*)sh.r.sce)[i] = ((const float4*)ce)[i];
    int k = npos * 3; if (k > D) k = D;
    __syncthreads();
    unsigned prefix = 0; int kk = k;
    for (int pass = 0; pass < 4; pass++) {
      int shift = 24 - 8 * pass;
      for (int i = tid; i < 16 * 256; i += NT) ((int*)sh.r.whist)[i] = 0;
      __syncthreads();
      unsigned himask = (pass == 0) ? 0u : (0xFFFFFFFFu << (shift + 8));
      for (int d = tid; d < D; d += NT) {
        unsigned keyb = __float_as_uint(sh.r.sce[d]);
        if ((keyb & himask) == (prefix & himask))
          atomicAdd(&sh.r.whist[wav][(keyb >> shift) & 255], 1);
      }
      __syncthreads();
      if (tid < 256) {
        int h = 0;
        #pragma unroll
        for (int w = 0; w < 16; w++) h += sh.r.whist[w][tid];
        sh.r.hist[tid] = h;
      }
      __syncthreads();
      if (tid < 64) {
        int l = tid;
        int h0 = sh.r.hist[l*4], h1 = sh.r.hist[l*4+1], h2 = sh.r.hist[l*4+2], h3 = sh.r.hist[l*4+3];
        int loc4 = h0 + h1 + h2 + h3;
        int suf = loc4;
        #pragma unroll
        for (int st = 1; st < 64; st <<= 1) {
          int o = __shfl_down(suf, st, 64);
          if (l + st < 64) suf += o;
        }
        int snext = suf - loc4;
        int s3 = snext + h3, s2 = s3 + h2, s1 = s2 + h1, s0 = s1 + h0;
        if (s3 >= kk && snext < kk) { sh.r.prefixSh = prefix | ((unsigned)(l*4+3) << shift); sh.r.kkSh = kk - snext; }
        if (s2 >= kk && s3 < kk)    { sh.r.prefixSh = prefix | ((unsigned)(l*4+2) << shift); sh.r.kkSh = kk - s3; }
        if (s1 >= kk && s2 < kk)    { sh.r.prefixSh = prefix | ((unsigned)(l*4+1) << shift); sh.r.kkSh = kk - s2; }
        if (s0 >= kk && s1 < kk)    { sh.r.prefixSh = prefix | ((unsigned)(l*4+0) << shift); sh.r.kkSh = kk - s1; }
      }
      __syncthreads();
      prefix = sh.r.prefixSh; kk = sh.r.kkSh;
      __syncthreads();
    }
    float T = __uint_as_float(prefix);
    double sgt = 0.0; int cgt = 0;
    for (int d = tid; d < D; d += NT) {
      float v = sh.r.sce[d];
      if (__float_as_uint(v) > prefix) { sgt += (double)v; cgt++; }
    }
    double wv = waveSumD(sgt);
    double wc = waveSumD((double)cgt);
    if (lane == 0) { sh.r.wsum[wav] = wv; sh.r.wcnt2[wav] = wc; }
    __syncthreads();
    if (tid == 0) {
      double tsg = 0, tcg = 0;
      #pragma unroll
      for (int w = 0; w < 16; w++) { tsg += sh.r.wsum[w]; tcg += sh.r.wcnt2[w]; }
      p.gCeNeg[bb] = tsg + ((double)k - tcg) * (double)T;
    }
  }
  __threadfence();
  gg.sync();                                   // S4: emb/nemb/qp/lab/gPc ready

  // ---- P4: pairs + triplet, block i = row i ----
  {
    int i = g;
    int qq = tid >> 8, j = tid & 255;
    if (tid == 0) { sh.q.pc = *p.gPc; sh.q.li = p.lab[i]; }
    if (tid < L) { sh.q.ei[tid] = p.emb[i * L + tid]; sh.q.ni[tid] = p.nemb[i * L + tid]; }
    if (tid >= L && tid < L + 3) sh.q.qi[tid - L] = p.qp[i * 3 + (tid - L)];
    __syncthreads();
    int Pc = sh.q.pc, li = sh.q.li;
    bool vi = (i < Pc);
    bool pp = false, np = false;
    double dsk = 0.0;
    if (qq == 0) {
      bool vj = (j < Pc);
      const float4* nj4 = (const float4*)(p.nemb + j * L);
      const float4* ej4 = (const float4*)(p.emb + j * L);
      float sq = 0.f, esq = 0.f;
      #pragma unroll
      for (int c = 0; c < 8; c++) {
        float4 nn = nj4[c], ee = ej4[c];
        float d0 = sh.q.ni[c*4+0] - nn.x, d1 = sh.q.ni[c*4+1] - nn.y;
        float d2 = sh.q.ni[c*4+2] - nn.z, d3 = sh.q.ni[c*4+3] - nn.w;
        sq += d0*d0 + d1*d1 + d2*d2 + d3*d3;
        float e0 = sh.q.ei[c*4+0] - ee.x, e1 = sh.q.ei[c*4+1] - ee.y;
        float e2 = sh.q.ei[c*4+2] - ee.z, e3 = sh.q.ei[c*4+3] - ee.w;
        esq += e0*e0 + e1*e1 + e2*e2 + e3*e3;
      }
      float dd = sqrtf(fmaxf(sq, 1e-12f));
      sh.q.sd[j] = dd;
      float qsq = 0.f;
      #pragma unroll
      for (int c = 0; c < 3; c++) { float dq = sh.q.qi[c] - p.qp[j * 3 + c]; qsq += dq * dq; }
      bool vp = vi && vj && (i != j);
      bool same = (li == p.lab[j]);
      pp = vp && same && (dd > 0.2f);
      np = vp && !same && (dd < 0.8f);
      float diff = esq - qsq;
      dsk = pp ? (double)diff * (double)diff : 0.0;
    }
    unsigned long long pb = __ballot(pp), nb = __ballot(np);
    double dw = waveSumD(dsk);
    if (lane == 0 && wav < 4) {
      sh.q.spm[wav] = pb; sh.q.snm[wav] = nb; sh.q.w1[wav] = dw;
      sh.q.ppc[wav] = (int)__popcll(pb); sh.q.npc[wav] = (int)__popcll(nb);
    }
    __syncthreads();
    unsigned long long pmw = sh.q.spm[j >> 6];
    bool pj = (pmw >> (j & 63)) & 1ull;
    float sdj = sh.q.sd[j];
    double ts = 0.0, tc = 0.0;
    if (pj) {
      for (int it = 0; it < 64; it++) {
        int kx = qq + 4 * it;
        unsigned long long nmw = sh.q.snm[kx >> 6];
        if ((nmw >> (kx & 63)) & 1ull) {
          float x = sdj - sh.q.sd[kx] + 0.2f;
          if (x > 0.f) { ts += (double)x; tc += 1.0; }
        }
      }
    }
    ts = waveSumD(ts); tc = waveSumD(tc);
    if (lane == 0) { sh.q.wS[wav] = ts; sh.q.wC[wav] = tc; }
    __syncthreads();
    if (tid == 0) {
      double S = 0, Cc = 0;
      #pragma unroll
      for (int w = 0; w < 16; w++) { S += sh.q.wS[w]; Cc += sh.q.wC[w]; }
      double dsum = sh.q.w1[0] + sh.q.w1[1] + sh.q.w1[2] + sh.q.w1[3];
      int pcnt = sh.q.ppc[0] + sh.q.ppc[1] + sh.q.ppc[2] + sh.q.ppc[3];
      int ncnt = sh.q.npc[0] + sh.q.npc[1] + sh.q.npc[2] + sh.q.npc[3];
      p.gDesk[i] = dsum; p.gNpp[i] = (double)pcnt; p.gNnp[i] = (double)ncnt;
      p.gTripS[i] = S; p.gTripC[i] = Cc;
    }
  }
  __threadfence();
  gg.sync();                                   // S5: all partials ready

  // ---- P5: block 0 reduces and writes out ----
  if (g == 0) {
    double lossL = blockSumD(p.gLossL, 256, sh.f.lbuf, tid);
    double lossP = blockSumD(p.gLossP, 256, sh.f.lbuf, tid);
    double ceP   = blockSumD(p.gCeP,   256, sh.f.lbuf, tid);
    double ceN   = blockSumD(p.gCeNeg,  B,  sh.f.lbuf, tid);
    double desk  = blockSumD(p.gDesk,  256, sh.f.lbuf, tid);
    double npp   = blockSumD(p.gNpp,   256, sh.f.lbuf, tid);
    double nnp   = blockSumD(p.gNnp,   256, sh.f.lbuf, tid);
    double tripS = blockSumD(p.gTripS, 256, sh.f.lbuf, tid);
    double tripC = blockSumD(p.gTripC, 256, sh.f.lbuf, tid);
    double Ntot  = blockSumI(p.cnt,    256, sh.f.lbuf, tid);
    if (tid == 0) {
      double N = (Ntot > 0.0) ? Ntot : 1.0;
      p.out[0] = (float)(lossL / N);
      p.out[1] = (float)((ceP + ceN) / N);
      p.out[2] = (float)(lossP / N);
      double cnt = (tripC > 0.0) ? tripC : 1.0;
      double loss_t = tripS / cnt;
      double nppd = (npp > 0.0) ? npp : 1.0;
      double tot = npp + nnp;
      double denom = (tot > 0.0) ? tot : 1.0;
      double Ldesk = desk / nppd + loss_t / denom;
      Ldesk = Ldesk / nppd / 32.0;
      p.out[3] = (float)Ldesk;
      p.out[4] = (float)loss_t;
    }
  }
}

extern "C" void kernel_launch(void* const* d_in, const int* in_sizes, int n_in,
                              void* d_out, int out_size, void* d_ws, size_t ws_size,
                              hipStream_t stream) {
  char* ws = (char*)d_ws;
  size_t off = 0;
  auto alloc = [&](size_t bytes) -> char* {
    char* q = ws + off;
    off += (bytes + 255) & ~(size_t)255;
    return q;
  };
  Params prm;
  prm.loc     = (const float*)d_in[0];
  prm.conf    = (const float*)d_in[1];
  prm.line    = (const float*)d_in[2];
  prm.pose    = (const float*)d_in[3];
  prm.dbox    = (const float*)d_in[4];
  prm.targets = (const float*)d_in[5];
  prm.out     = (float*)d_out;
  prm.bp       = (unsigned long long*)alloc(GRID * 8);
  prm.cnt      = (int*)alloc(GRID * 4);
  prm.posSlice = (int*)alloc(GRID * 256 * 4);
  prm.sce      = (float*)alloc((size_t)B * D * 4);
  prm.gLossL   = (double*)alloc(256 * 8);
  prm.gLossP   = (double*)alloc(256 * 8);
  prm.gCeP     = (double*)alloc(256 * 8);
  prm.gCeNeg   = (double*)alloc(B * 8);
  prm.gDesk    = (double*)alloc(256 * 8);
  prm.gNpp     = (double*)alloc(256 * 8);
  prm.gNnp     = (double*)alloc(256 * 8);
  prm.gTripS   = (double*)alloc(256 * 8);
  prm.gTripC   = (double*)alloc(256 * 8);
  prm.gPc      = (int*)alloc(256);
  prm.emb      = (float*)alloc(256 * L * 4);
  prm.nemb     = (float*)alloc(256 * L * 4);
  prm.qp       = (float*)alloc(256 * 3 * 4);
  prm.lab      = (int*)alloc(256 * 4);

  void* args[] = { &prm };
  hipLaunchCooperativeKernel((void*)k_mega, dim3(GRID), dim3(NT), args, 0, stream);
}

// Round 8
// 163.078 us; speedup vs baseline: 4.0128x; 4.0128x over previous
//
#include <hip/hip_runtime.h>
#include <cstdint>

#define B 32
#define D 8732
#define C 21
#define L 32
#define O 8
#define NS 8
#define SLICE 1092     // ceil(D/8)
#define NT 1024

struct Ws {
  const float *loc, *conf, *line, *pose, *dbox, *targets;
  float* out;
  int* cnt;                 // 256 per-(b,slice) positive count (uncapped)
  int* posSlice;            // 256*256 packed (d | cls<<14 | bi<<19)
  float* sce;               // B*D mined-ce
  double *gLossL, *gLossP, *gCeP;                  // 256 partials
  double *gCeNeg;                                  // 32
  double *gDesk, *gNpp, *gNnp, *gTripS, *gTripC;   // 256
  int* gPc;                 // 1
  float *emb, *nemb, *qp; int* lab;                // 256-row gathered
};

__device__ inline double waveSumD(double v) {
  #pragma unroll
  for (int s = 32; s > 0; s >>= 1) v += __shfl_down(v, s, 64);
  return v;
}

__device__ inline float iou_one(float tx1, float ty1, float tx2, float ty2, float ta,
                                float px1, float py1, float px2, float py2, float areaB) {
  float lx = fmaxf(tx1, px1), ly = fmaxf(ty1, py1);
  float rx = fminf(tx2, px2), ry = fminf(ty2, py2);
  float iw = fmaxf(rx - lx, 0.f), ih = fmaxf(ry - ly, 0.f);
  float inter = iw * ih;
  return inter / (ta + areaB - inter);
}

// ============ K1: per-slice match/CE/losses/compaction (256 blocks) ============
// bestprior for the whole batch is recomputed redundantly in-block (~3 us VALU)
// to avoid a kernel boundary or cross-block atomics.
__global__ __launch_bounds__(NT) void k_slice(Ws p) {
  __shared__ float tb[O][4], ta[O], tl[O], tp_[O][3];
  __shared__ int bpd[O];
  __shared__ unsigned long long wm[16][O];
  __shared__ int plist[256];
  __shared__ int wcnt[16], wbase[16];
  __shared__ double wred[16][3];
  __shared__ int run;
  int g = blockIdx.x, tid = threadIdx.x;
  int lane = tid & 63, wav = tid >> 6;
  const unsigned long long lt = (lane == 0) ? 0ull : (~0ull >> (64 - lane));
  int b = g >> 3, s = g & 7;
  int dBeg = s * SLICE;
  int dEnd = dBeg + SLICE; if (dEnd > D) dEnd = D;

  if (tid < O) {
    const float* tr = p.targets + ((size_t)b * O + tid) * 9;
    tb[tid][0] = tr[0]; tb[tid][1] = tr[1]; tb[tid][2] = tr[2]; tb[tid][3] = tr[3];
    ta[tid] = (tr[2] - tr[0]) * (tr[3] - tr[1]);
    tl[tid] = tr[4];
    tp_[tid][0] = tr[5]; tp_[tid][1] = tr[6]; tp_[tid][2] = tr[7];
  }
  if (tid == 0) run = 0;
  __syncthreads();

  // ---- per-truth best prior over FULL D, fully in-block ----
  {
    unsigned long long key[O];
    #pragma unroll
    for (int t = 0; t < O; t++) key[t] = 0ull;
    for (int d = tid; d < D; d += NT) {
      float4 db = *(const float4*)(p.dbox + (size_t)d * 4);
      float px1 = db.x - 0.5f*db.z, py1 = db.y - 0.5f*db.w;
      float px2 = db.x + 0.5f*db.z, py2 = db.y + 0.5f*db.w;
      float areaB = db.z * db.w;
      #pragma unroll
      for (int t = 0; t < O; t++) {
        float iou = iou_one(tb[t][0], tb[t][1], tb[t][2], tb[t][3], ta[t],
                            px1, py1, px2, py2, areaB);
        unsigned long long kk = ((unsigned long long)__float_as_uint(iou) << 32)
                              | (unsigned long long)(0xFFFFFFFFu - (unsigned)d); // tie -> smaller d
        if (kk > key[t]) key[t] = kk;
      }
    }
    #pragma unroll
    for (int t = 0; t < O; t++) {
      unsigned long long k = key[t];
      #pragma unroll
      for (int sft = 32; sft > 0; sft >>= 1) {
        unsigned long long o = __shfl_down(k, sft, 64);
        if (o > k) k = o;
      }
      if (lane == 0) wm[wav][t] = k;
    }
    __syncthreads();
    if (tid < O) {
      unsigned long long k = wm[0][tid];
      #pragma unroll
      for (int w = 1; w < 16; w++) if (wm[w][tid] > k) k = wm[w][tid];
      bpd[tid] = (int)(0xFFFFFFFFu - (unsigned)(k & 0xFFFFFFFFull));
    }
    __syncthreads();
  }

  // ---- slice loop: match, CE, loc/pose losses, stable compaction ----
  double ll = 0, lp = 0, cp = 0;
  for (int d0 = dBeg; d0 < dEnd; d0 += NT) {
    int d = d0 + tid;
    bool act = d < dEnd;
    int cls = 0, bi = 0;
    if (act) {
      float4 db = *(const float4*)(p.dbox + (size_t)d * 4);
      float px1 = db.x - 0.5f*db.z, py1 = db.y - 0.5f*db.w;
      float px2 = db.x + 0.5f*db.z, py2 = db.y + 0.5f*db.w;
      float areaB = db.z * db.w;
      float bv = -1.0f;
      #pragma unroll
      for (int t = 0; t < O; t++) {
        float iou = iou_one(tb[t][0], tb[t][1], tb[t][2], tb[t][3], ta[t],
                            px1, py1, px2, py2, areaB);
        if (iou > bv) { bv = iou; bi = t; }     // argmax axis=0: first max wins
      }
      #pragma unroll
      for (int t = O - 1; t >= 0; t--)          // numpy scatter: last truth wins
        if (bpd[t] == d) { bi = t; bv = 2.0f; break; }
      cls = (bv < 0.5f) ? 0 : ((int)tl[bi] + 1);
      const float* cb = p.conf + ((size_t)b * D + d) * C;
      float x[C];
      #pragma unroll
      for (int c = 0; c < C; c++) x[c] = cb[c];
      float m = x[0];
      #pragma unroll
      for (int c = 1; c < C; c++) m = fmaxf(m, x[c]);
      float sm = 0.f;
      #pragma unroll
      for (int c = 0; c < C; c++) sm += __expf(x[c] - m);
      float xc = x[0];
      #pragma unroll
      for (int c = 1; c < C; c++) xc = (cls == c) ? x[c] : xc;
      float ce = m + __logf(sm) - xc;
      size_t bd = (size_t)b * D + d;
      if (cls > 0) {
        cp += ce;
        p.sce[bd] = 0.f;
        float g0 = ((tb[bi][0] + tb[bi][2]) * 0.5f - db.x) / (0.1f * db.z);
        float g1 = ((tb[bi][1] + tb[bi][3]) * 0.5f - db.y) / (0.1f * db.w);
        float g2 = logf((tb[bi][2] - tb[bi][0]) / db.z) / 0.2f;
        float g3 = logf((tb[bi][3] - tb[bi][1]) / db.w) / 0.2f;
        float4 lo = *(const float4*)(p.loc + bd * 4);
        float dv, a;
        dv = lo.x - g0; a = fabsf(dv); ll += (double)((a < 1.f) ? 0.5f*dv*dv : a - 0.5f);
        dv = lo.y - g1; a = fabsf(dv); ll += (double)((a < 1.f) ? 0.5f*dv*dv : a - 0.5f);
        dv = lo.z - g2; a = fabsf(dv); ll += (double)((a < 1.f) ? 0.5f*dv*dv : a - 0.5f);
        dv = lo.w - g3; a = fabsf(dv); ll += (double)((a < 1.f) ? 0.5f*dv*dv : a - 0.5f);
        const float* po = p.pose + bd * 3;
        #pragma unroll
        for (int q = 0; q < 3; q++) {
          float pd = po[q] - tp_[bi][q];
          lp += (double)pd * (double)pd;
        }
      } else {
        p.sce[bd] = fmaxf(ce, 0.f);
      }
    }
    bool pos = act && (cls > 0);
    unsigned long long mm = __ballot(pos);
    if (lane == 0) wcnt[wav] = __popcll(mm);
    __syncthreads();
    if (tid == 0) {
      int r = run;
      #pragma unroll
      for (int w = 0; w < 16; w++) { wbase[w] = r; r += wcnt[w]; }
      run = r;
    }
    __syncthreads();
    if (pos) {
      int rank = wbase[wav] + __popcll(mm & lt);
      if (rank < 256) plist[rank] = d | (cls << 14) | (bi << 19);
    }
    __syncthreads();
  }
  int tot = run;
  if (tid == 0) p.cnt[g] = tot;
  int stored = (tot < 256) ? tot : 256;
  if (tid < stored) p.posSlice[g * 256 + tid] = plist[tid];
  double a0 = waveSumD(ll), a1 = waveSumD(lp), a2 = waveSumD(cp);
  if (lane == 0) { wred[wav][0] = a0; wred[wav][1] = a1; wred[wav][2] = a2; }
  __syncthreads();
  if (tid == 0) {
    double tll = 0, tlp = 0, tcp = 0;
    #pragma unroll
    for (int w = 0; w < 16; w++) { tll += wred[w][0]; tlp += wred[w][1]; tcp += wred[w][2]; }
    p.gLossL[g] = tll; p.gLossP[g] = tlp; p.gCeP[g] = tcp;
  }
}

// ============ K2: per-batch radix top-k + positive gather (32 blocks) ============
__global__ __launch_bounds__(NT) void k_batch(Ws p) {
  __shared__ __align__(16) float sce[D];
  __shared__ int whist[16][256];
  __shared__ int hist[256];
  __shared__ int sc[256];
  __shared__ int p8[NS + 1];
  __shared__ int gbS;
  __shared__ unsigned prefixSh; __shared__ int kkSh;
  __shared__ double wsum[16], wcnt2[16];
  int bb = blockIdx.x, tid = threadIdx.x;
  int lane = tid & 63, wav = tid >> 6;
  if (tid < 256) sc[tid] = p.cnt[tid];
  __syncthreads();
  if (tid == 0) {
    int gb = 0;
    for (int i = 0; i < bb * NS; i++) gb += sc[i];
    gbS = gb;
    int run = 0;
    for (int ss = 0; ss < NS; ss++) { p8[ss] = run; run += sc[bb * NS + ss]; }
    p8[NS] = run;                             // npos of this batch
    if (bb == 0) {
      int totAll = 0;
      for (int i = 0; i < 256; i++) totAll += sc[i];
      *p.gPc = (totAll < 256) ? totAll : 256;
    }
  }
  __syncthreads();
  int gb = gbS, npos = p8[NS];
  int nr = (npos < 256) ? npos : 256;
  if (tid < nr) {
    int r = tid, ss = 0;
    #pragma unroll
    for (int q = 1; q < NS; q++) if (r >= p8[q]) ss = q;
    int idx = r - p8[ss];
    int slot = gb + r;
    if (idx < 256 && slot < 256) {
      int packed = p.posSlice[(bb * NS + ss) * 256 + idx];
      int d   = packed & 0x3FFF;
      int cls = (packed >> 14) & 31;
      int bi  = (packed >> 19) & 7;
      size_t flat = (size_t)bb * D + d;
      const float4* e4 = (const float4*)(p.line + flat * L);
      float4* o4 = (float4*)(p.emb + slot * L);
      float4* n4 = (float4*)(p.nemb + slot * L);
      float4 v[8];
      float nrm2 = 0.f;
      #pragma unroll
      for (int c = 0; c < 8; c++) {
        v[c] = e4[c];
        o4[c] = v[c];
        nrm2 += v[c].x*v[c].x + v[c].y*v[c].y + v[c].z*v[c].z + v[c].w*v[c].w;
      }
      float inv = 1.f / fmaxf(sqrtf(nrm2), 1e-12f);
      #pragma unroll
      for (int c = 0; c < 8; c++) {
        float4 t = v[c];
        t.x *= inv; t.y *= inv; t.z *= inv; t.w *= inv;
        n4[c] = t;
      }
      p.lab[slot] = cls;
      const float* tr = p.targets + ((size_t)bb * O + bi) * 9;
      p.qp[slot * 3 + 0] = tr[5]; p.qp[slot * 3 + 1] = tr[6]; p.qp[slot * 3 + 2] = tr[7];
    }
  }
  // radix top-k over this batch's mined ce (k = 3*npos)
  const float* ce = p.sce + (size_t)bb * D;
  for (int i = tid; i < D / 4; i += NT)
    ((float4*)sce)[i] = ((const float4*)ce)[i];
  int k = npos * 3; if (k > D) k = D;
  __syncthreads();
  unsigned prefix = 0; int kk = k;            // kk >= 1 (npos >= 1 via forced matches)
  for (int pass = 0; pass < 4; pass++) {
    int shift = 24 - 8 * pass;
    for (int i = tid; i < 16 * 256; i += NT) ((int*)whist)[i] = 0;
    __syncthreads();
    unsigned himask = (pass == 0) ? 0u : (0xFFFFFFFFu << (shift + 8));
    for (int d = tid; d < D; d += NT) {
      unsigned keyb = __float_as_uint(sce[d]);
      if ((keyb & himask) == (prefix & himask))
        atomicAdd(&whist[wav][(keyb >> shift) & 255], 1);
    }
    __syncthreads();
    if (tid < 256) {
      int h = 0;
      #pragma unroll
      for (int w = 0; w < 16; w++) h += whist[w][tid];
      hist[tid] = h;
    }
    __syncthreads();
    if (tid < 64) {
      int l = tid;
      int h0 = hist[l*4], h1 = hist[l*4+1], h2 = hist[l*4+2], h3 = hist[l*4+3];
      int loc4 = h0 + h1 + h2 + h3;
      int suf = loc4;
      #pragma unroll
      for (int st = 1; st < 64; st <<= 1) {
        int o = __shfl_down(suf, st, 64);
        if (l + st < 64) suf += o;
      }
      int snext = suf - loc4;
      int s3 = snext + h3, s2 = s3 + h2, s1 = s2 + h1, s0 = s1 + h0;
      if (s3 >= kk && snext < kk) { prefixSh = prefix | ((unsigned)(l*4+3) << shift); kkSh = kk - snext; }
      if (s2 >= kk && s3 < kk)    { prefixSh = prefix | ((unsigned)(l*4+2) << shift); kkSh = kk - s3; }
      if (s1 >= kk && s2 < kk)    { prefixSh = prefix | ((unsigned)(l*4+1) << shift); kkSh = kk - s2; }
      if (s0 >= kk && s1 < kk)    { prefixSh = prefix | ((unsigned)(l*4+0) << shift); kkSh = kk - s1; }
    }
    __syncthreads();
    prefix = prefixSh; kk = kkSh;
    __syncthreads();
  }
  float T = __uint_as_float(prefix);
  double sgt = 0.0; int cgt = 0;
  for (int d = tid; d < D; d += NT) {
    float v = sce[d];
    if (__float_as_uint(v) > prefix) { sgt += (double)v; cgt++; }
  }
  double wv = waveSumD(sgt);
  double wc = waveSumD((double)cgt);
  if (lane == 0) { wsum[wav] = wv; wcnt2[wav] = wc; }
  __syncthreads();
  if (tid == 0) {
    double tsg = 0, tcg = 0;
    #pragma unroll
    for (int w = 0; w < 16; w++) { tsg += wsum[w]; tcg += wcnt2[w]; }
    p.gCeNeg[bb] = tsg + ((double)k - tcg) * (double)T;
  }
}

// ============ K3: pairs + triplet, block i = row i (256 blocks) ============
__global__ __launch_bounds__(NT) void k_pt2(Ws p) {
  __shared__ float ei[L], ni[L], qi[3];
  __shared__ float sd[256];
  __shared__ unsigned long long spm[4], snm[4];
  __shared__ double w1[4];
  __shared__ int ppc[4], npc[4];
  __shared__ double wS[16], wC[16];
  __shared__ int liS, pcS;
  int i = blockIdx.x, tid = threadIdx.x;
  int lane = tid & 63, wav = tid >> 6;
  int qq = tid >> 8, j = tid & 255;
  if (tid == 0) { pcS = *p.gPc; liS = p.lab[i]; }
  if (tid < L) { ei[tid] = p.emb[i * L + tid]; ni[tid] = p.nemb[i * L + tid]; }
  if (tid >= L && tid < L + 3) qi[tid - L] = p.qp[i * 3 + (tid - L)];
  __syncthreads();
  int Pc = pcS, li = liS;
  bool vi = (i < Pc);
  bool pp = false, np = false;
  double dsk = 0.0;
  if (qq == 0) {
    bool vj = (j < Pc);
    const float4* nj4 = (const float4*)(p.nemb + j * L);
    const float4* ej4 = (const float4*)(p.emb + j * L);
    float sq = 0.f, esq = 0.f;
    #pragma unroll
    for (int c = 0; c < 8; c++) {
      float4 nn = nj4[c], ee = ej4[c];
      float d0 = ni[c*4+0] - nn.x, d1 = ni[c*4+1] - nn.y;
      float d2 = ni[c*4+2] - nn.z, d3 = ni[c*4+3] - nn.w;
      sq += d0*d0 + d1*d1 + d2*d2 + d3*d3;
      float e0 = ei[c*4+0] - ee.x, e1 = ei[c*4+1] - ee.y;
      float e2 = ei[c*4+2] - ee.z, e3 = ei[c*4+3] - ee.w;
      esq += e0*e0 + e1*e1 + e2*e2 + e3*e3;
    }
    float dd = sqrtf(fmaxf(sq, 1e-12f));
    sd[j] = dd;
    float qsq = 0.f;
    #pragma unroll
    for (int c = 0; c < 3; c++) { float dq = qi[c] - p.qp[j * 3 + c]; qsq += dq * dq; }
    bool vp = vi && vj && (i != j);
    bool same = (li == p.lab[j]);
    pp = vp && same && (dd > 0.2f);
    np = vp && !same && (dd < 0.8f);
    float diff = esq - qsq;
    dsk = pp ? (double)diff * (double)diff : 0.0;
  }
  unsigned long long pb = __ballot(pp), nb = __ballot(np);
  double dw = waveSumD(dsk);
  if (lane == 0 && wav < 4) {
    spm[wav] = pb; snm[wav] = nb; w1[wav] = dw;
    ppc[wav] = (int)__popcll(pb); npc[wav] = (int)__popcll(nb);
  }
  __syncthreads();
  unsigned long long pmw = spm[j >> 6];
  bool pj = (pmw >> (j & 63)) & 1ull;
  float sdj = sd[j];
  double ts = 0.0, tc = 0.0;
  if (pj) {
    for (int it = 0; it < 64; it++) {
      int kx = qq + 4 * it;
      unsigned long long nmw = snm[kx >> 6];
      if ((nmw >> (kx & 63)) & 1ull) {
        float x = sdj - sd[kx] + 0.2f;
        if (x > 0.f) { ts += (double)x; tc += 1.0; }
      }
    }
  }
  ts = waveSumD(ts); tc = waveSumD(tc);
  if (lane == 0) { wS[wav] = ts; wC[wav] = tc; }
  __syncthreads();
  if (tid == 0) {
    double S = 0, Cc = 0;
    #pragma unroll
    for (int w = 0; w < 16; w++) { S += wS[w]; Cc += wC[w]; }
    double dsum = w1[0] + w1[1] + w1[2] + w1[3];
    int pcnt = ppc[0] + ppc[1] + ppc[2] + ppc[3];
    int ncnt = npc[0] + npc[1] + npc[2] + npc[3];
    p.gDesk[i] = dsum; p.gNpp[i] = (double)pcnt; p.gNnp[i] = (double)ncnt;
    p.gTripS[i] = S; p.gTripC[i] = Cc;
  }
}

// ============ K4: final reduce (1 block, 256 thr) ============
__global__ __launch_bounds__(256) void k_fin(Ws p) {
  __shared__ double lbuf[4];
  int tid = threadIdx.x;
  auto sumD = [&](const double* a, int n) -> double {
    double v = 0;
    for (int i = tid; i < n; i += 256) v += a[i];
    v = waveSumD(v);
    __syncthreads();
    if ((tid & 63) == 0) lbuf[tid >> 6] = v;
    __syncthreads();
    double r = lbuf[0] + lbuf[1] + lbuf[2] + lbuf[3];
    __syncthreads();
    return r;
  };
  double lossL = sumD(p.gLossL, 256);
  double lossP = sumD(p.gLossP, 256);
  double ceP   = sumD(p.gCeP,   256);
  double ceN   = sumD(p.gCeNeg,  B);
  double desk  = sumD(p.gDesk,  256);
  double npp   = sumD(p.gNpp,   256);
  double nnp   = sumD(p.gNnp,   256);
  double tripS = sumD(p.gTripS, 256);
  double tripC = sumD(p.gTripC, 256);
  double Ntot;
  {
    double v = 0;
    for (int i = tid; i < 256; i += 256) v += (double)p.cnt[i];
    v = waveSumD(v);
    __syncthreads();
    if ((tid & 63) == 0) lbuf[tid >> 6] = v;
    __syncthreads();
    Ntot = lbuf[0] + lbuf[1] + lbuf[2] + lbuf[3];
  }
  if (tid == 0) {
    double N = (Ntot > 0.0) ? Ntot : 1.0;
    p.out[0] = (float)(lossL / N);
    p.out[1] = (float)((ceP + ceN) / N);
    p.out[2] = (float)(lossP / N);
    double cnt = (tripC > 0.0) ? tripC : 1.0;
    double loss_t = tripS / cnt;
    double nppd = (npp > 0.0) ? npp : 1.0;
    double tot = npp + nnp;
    double denom = (tot > 0.0) ? tot : 1.0;
    double Ldesk = desk / nppd + loss_t / denom;
    Ldesk = Ldesk / nppd / 32.0;
    p.out[3] = (float)Ldesk;
    p.out[4] = (float)loss_t;
  }
}

extern "C" void kernel_launch(void* const* d_in, const int* in_sizes, int n_in,
                              void* d_out, int out_size, void* d_ws, size_t ws_size,
                              hipStream_t stream) {
  char* ws = (char*)d_ws;
  size_t off = 0;
  auto alloc = [&](size_t bytes) -> char* {
    char* q = ws + off;
    off += (bytes + 255) & ~(size_t)255;
    return q;
  };
  Ws p;
  p.loc     = (const float*)d_in[0];
  p.conf    = (const float*)d_in[1];
  p.line    = (const float*)d_in[2];
  p.pose    = (const float*)d_in[3];
  p.dbox    = (const float*)d_in[4];
  p.targets = (const float*)d_in[5];
  p.out     = (float*)d_out;
  p.cnt      = (int*)alloc(256 * 4);
  p.posSlice = (int*)alloc(256 * 256 * 4);
  p.sce      = (float*)alloc((size_t)B * D * 4);
  p.gLossL   = (double*)alloc(256 * 8);
  p.gLossP   = (double*)alloc(256 * 8);
  p.gCeP     = (double*)alloc(256 * 8);
  p.gCeNeg   = (double*)alloc(B * 8);
  p.gDesk    = (double*)alloc(256 * 8);
  p.gNpp     = (double*)alloc(256 * 8);
  p.gNnp     = (double*)alloc(256 * 8);
  p.gTripS   = (double*)alloc(256 * 8);
  p.gTripC   = (double*)alloc(256 * 8);
  p.gPc      = (int*)alloc(256);
  p.emb      = (float*)alloc(256 * L * 4);
  p.nemb     = (float*)alloc(256 * L * 4);
  p.qp       = (float*)alloc(256 * 3 * 4);
  p.lab      = (int*)alloc(256 * 4);

  // no memset: every workspace word consumed is written unconditionally first
  k_slice<<<256, NT, 0, stream>>>(p);
  k_batch<<<B,   NT, 0, stream>>>(p);
  k_pt2  <<<256, NT, 0, stream>>>(p);
  k_fin  <<<1,  256, 0, stream>>>(p);
}

// Round 9
// 155.026 us; speedup vs baseline: 4.2212x; 1.0519x over previous
//
#include <hip/hip_runtime.h>
#include <cstdint>

#define B 32
#define D 8732
#define C 21
#define L 32
#define O 8
#define NS 8
#define SLICE 1092     // ceil(D/8)
#define NT 1024

struct Ws {
  const float *loc, *conf, *line, *pose, *dbox, *targets;
  float* out;
  unsigned long long* bp;   // B*O per-truth best-prior packed keys
  int* cnt;                 // 256 per-(b,slice) positive count (uncapped)
  int* posSlice;            // 256*256 packed (d | cls<<14 | bi<<19)
  float* sce;               // B*D mined-ce
  double *gLossL, *gLossP, *gCeP;                  // 256 partials
  double *gCeNeg;                                  // 32
  double *gDesk, *gNpp, *gNnp, *gTripS, *gTripC;   // 256
  int* gPc;                 // 1
  float *emb, *nemb, *qp; int* lab;                // 256-row gathered
};

__device__ inline double waveSumD(double v) {
  #pragma unroll
  for (int s = 32; s > 0; s >>= 1) v += __shfl_down(v, s, 64);
  return v;
}

__device__ inline float iou_one(float tx1, float ty1, float tx2, float ty2, float ta,
                                float px1, float py1, float px2, float py2, float areaB) {
  float lx = fmaxf(tx1, px1), ly = fmaxf(ty1, py1);
  float rx = fminf(tx2, px2), ry = fminf(ty2, py2);
  float iw = fmaxf(rx - lx, 0.f), ih = fmaxf(ry - ly, 0.f);
  float inter = iw * ih;
  return inter / (ta + areaB - inter);
}

// ============ K0: per-truth best prior, slice-parallel atomicMax ============
// 256 blocks (8 slices x 32 batches) x 256 thr. bp zeroed via memsetAsync.
__global__ __launch_bounds__(256) void k_bp(Ws p) {
  __shared__ float tb[O][4], ta[O];
  __shared__ unsigned long long wm[4][O];
  int g = blockIdx.x, tid = threadIdx.x;
  int lane = tid & 63, wav = tid >> 6;
  int b = g >> 3, s = g & 7;
  int dBeg = s * SLICE;
  int dEnd = dBeg + SLICE; if (dEnd > D) dEnd = D;
  if (tid < O) {
    const float* tr = p.targets + ((size_t)b * O + tid) * 9;
    tb[tid][0] = tr[0]; tb[tid][1] = tr[1]; tb[tid][2] = tr[2]; tb[tid][3] = tr[3];
    ta[tid] = (tr[2] - tr[0]) * (tr[3] - tr[1]);
  }
  __syncthreads();
  unsigned long long key[O];
  #pragma unroll
  for (int t = 0; t < O; t++) key[t] = 0ull;
  for (int d = dBeg + tid; d < dEnd; d += 256) {
    float4 db = *(const float4*)(p.dbox + (size_t)d * 4);
    float px1 = db.x - 0.5f*db.z, py1 = db.y - 0.5f*db.w;
    float px2 = db.x + 0.5f*db.z, py2 = db.y + 0.5f*db.w;
    float areaB = db.z * db.w;
    #pragma unroll
    for (int t = 0; t < O; t++) {
      float iou = iou_one(tb[t][0], tb[t][1], tb[t][2], tb[t][3], ta[t],
                          px1, py1, px2, py2, areaB);
      unsigned long long kk = ((unsigned long long)__float_as_uint(iou) << 32)
                            | (unsigned long long)(0xFFFFFFFFu - (unsigned)d); // tie -> smaller d
      if (kk > key[t]) key[t] = kk;
    }
  }
  #pragma unroll
  for (int t = 0; t < O; t++) {
    unsigned long long k = key[t];
    #pragma unroll
    for (int sft = 32; sft > 0; sft >>= 1) {
      unsigned long long o = __shfl_down(k, sft, 64);
      if (o > k) k = o;
    }
    if (lane == 0) wm[wav][t] = k;
  }
  __syncthreads();
  if (tid < O) {
    unsigned long long k = wm[0][tid];
    #pragma unroll
    for (int w = 1; w < 4; w++) if (wm[w][tid] > k) k = wm[w][tid];
    atomicMax(&p.bp[b * O + tid], k);
  }
}

// ============ K1: per-slice match/CE/losses/compaction (256 blocks) ============
__global__ __launch_bounds__(NT) void k_slice(Ws p) {
  __shared__ float tb[O][4], ta[O], tl[O], tp_[O][3];
  __shared__ int bpd[O];
  __shared__ int plist[256];
  __shared__ int wcnt[16], wbase[16];
  __shared__ double wred[16][3];
  __shared__ int run;
  int g = blockIdx.x, tid = threadIdx.x;
  int lane = tid & 63, wav = tid >> 6;
  const unsigned long long lt = (lane == 0) ? 0ull : (~0ull >> (64 - lane));
  int b = g >> 3, s = g & 7;
  int dBeg = s * SLICE;
  int dEnd = dBeg + SLICE; if (dEnd > D) dEnd = D;

  if (tid < O) {
    const float* tr = p.targets + ((size_t)b * O + tid) * 9;
    tb[tid][0] = tr[0]; tb[tid][1] = tr[1]; tb[tid][2] = tr[2]; tb[tid][3] = tr[3];
    ta[tid] = (tr[2] - tr[0]) * (tr[3] - tr[1]);
    tl[tid] = tr[4];
    tp_[tid][0] = tr[5]; tp_[tid][1] = tr[6]; tp_[tid][2] = tr[7];
  }
  if (tid >= 64 && tid < 64 + O) {
    unsigned long long k = p.bp[b * O + (tid - 64)];
    bpd[tid - 64] = (int)(0xFFFFFFFFu - (unsigned)(k & 0xFFFFFFFFull));
  }
  if (tid == 0) run = 0;
  __syncthreads();

  // ---- slice loop: match, CE, loc/pose losses, stable compaction ----
  double ll = 0, lp = 0, cp = 0;
  for (int d0 = dBeg; d0 < dEnd; d0 += NT) {
    int d = d0 + tid;
    bool act = d < dEnd;
    int cls = 0, bi = 0;
    if (act) {
      float4 db = *(const float4*)(p.dbox + (size_t)d * 4);
      float px1 = db.x - 0.5f*db.z, py1 = db.y - 0.5f*db.w;
      float px2 = db.x + 0.5f*db.z, py2 = db.y + 0.5f*db.w;
      float areaB = db.z * db.w;
      float bv = -1.0f;
      #pragma unroll
      for (int t = 0; t < O; t++) {
        float iou = iou_one(tb[t][0], tb[t][1], tb[t][2], tb[t][3], ta[t],
                            px1, py1, px2, py2, areaB);
        if (iou > bv) { bv = iou; bi = t; }     // argmax axis=0: first max wins
      }
      #pragma unroll
      for (int t = O - 1; t >= 0; t--)          // numpy scatter: last truth wins
        if (bpd[t] == d) { bi = t; bv = 2.0f; break; }
      cls = (bv < 0.5f) ? 0 : ((int)tl[bi] + 1);
      const float* cb = p.conf + ((size_t)b * D + d) * C;
      float x[C];
      #pragma unroll
      for (int c = 0; c < C; c++) x[c] = cb[c];
      float m = x[0];
      #pragma unroll
      for (int c = 1; c < C; c++) m = fmaxf(m, x[c]);
      float sm = 0.f;
      #pragma unroll
      for (int c = 0; c < C; c++) sm += __expf(x[c] - m);
      float xc = x[0];
      #pragma unroll
      for (int c = 1; c < C; c++) xc = (cls == c) ? x[c] : xc;
      float ce = m + __logf(sm) - xc;
      size_t bd = (size_t)b * D + d;
      if (cls > 0) {
        cp += ce;
        p.sce[bd] = 0.f;
        float g0 = ((tb[bi][0] + tb[bi][2]) * 0.5f - db.x) / (0.1f * db.z);
        float g1 = ((tb[bi][1] + tb[bi][3]) * 0.5f - db.y) / (0.1f * db.w);
        float g2 = logf((tb[bi][2] - tb[bi][0]) / db.z) / 0.2f;
        float g3 = logf((tb[bi][3] - tb[bi][1]) / db.w) / 0.2f;
        float4 lo = *(const float4*)(p.loc + bd * 4);
        float dv, a;
        dv = lo.x - g0; a = fabsf(dv); ll += (double)((a < 1.f) ? 0.5f*dv*dv : a - 0.5f);
        dv = lo.y - g1; a = fabsf(dv); ll += (double)((a < 1.f) ? 0.5f*dv*dv : a - 0.5f);
        dv = lo.z - g2; a = fabsf(dv); ll += (double)((a < 1.f) ? 0.5f*dv*dv : a - 0.5f);
        dv = lo.w - g3; a = fabsf(dv); ll += (double)((a < 1.f) ? 0.5f*dv*dv : a - 0.5f);
        const float* po = p.pose + bd * 3;
        #pragma unroll
        for (int q = 0; q < 3; q++) {
          float pd = po[q] - tp_[bi][q];
          lp += (double)pd * (double)pd;
        }
      } else {
        p.sce[bd] = fmaxf(ce, 0.f);
      }
    }
    bool pos = act && (cls > 0);
    unsigned long long mm = __ballot(pos);
    if (lane == 0) wcnt[wav] = __popcll(mm);
    __syncthreads();
    if (tid == 0) {
      int r = run;
      #pragma unroll
      for (int w = 0; w < 16; w++) { wbase[w] = r; r += wcnt[w]; }
      run = r;
    }
    __syncthreads();
    if (pos) {
      int rank = wbase[wav] + __popcll(mm & lt);
      if (rank < 256) plist[rank] = d | (cls << 14) | (bi << 19);
    }
    __syncthreads();
  }
  int tot = run;
  if (tid == 0) p.cnt[g] = tot;
  int stored = (tot < 256) ? tot : 256;
  if (tid < stored) p.posSlice[g * 256 + tid] = plist[tid];
  double a0 = waveSumD(ll), a1 = waveSumD(lp), a2 = waveSumD(cp);
  if (lane == 0) { wred[wav][0] = a0; wred[wav][1] = a1; wred[wav][2] = a2; }
  __syncthreads();
  if (tid == 0) {
    double tll = 0, tlp = 0, tcp = 0;
    #pragma unroll
    for (int w = 0; w < 16; w++) { tll += wred[w][0]; tlp += wred[w][1]; tcp += wred[w][2]; }
    p.gLossL[g] = tll; p.gLossP[g] = tlp; p.gCeP[g] = tcp;
  }
}

// ============ K2: per-batch radix top-k + positive gather (32 blocks) ============
__global__ __launch_bounds__(NT) void k_batch(Ws p) {
  __shared__ __align__(16) float sce[D];
  __shared__ int whist[16][256];
  __shared__ int hist[256];
  __shared__ int sc[256];
  __shared__ int p8[NS + 1];
  __shared__ int gbS;
  __shared__ unsigned prefixSh; __shared__ int kkSh;
  __shared__ double wsum[16], wcnt2[16];
  int bb = blockIdx.x, tid = threadIdx.x;
  int lane = tid & 63, wav = tid >> 6;
  if (tid < 256) sc[tid] = p.cnt[tid];
  __syncthreads();
  if (tid == 0) {
    int gb = 0;
    for (int i = 0; i < bb * NS; i++) gb += sc[i];
    gbS = gb;
    int run = 0;
    for (int ss = 0; ss < NS; ss++) { p8[ss] = run; run += sc[bb * NS + ss]; }
    p8[NS] = run;                             // npos of this batch
    if (bb == 0) {
      int totAll = 0;
      for (int i = 0; i < 256; i++) totAll += sc[i];
      *p.gPc = (totAll < 256) ? totAll : 256;
    }
  }
  __syncthreads();
  int gb = gbS, npos = p8[NS];
  int nr = (npos < 256) ? npos : 256;
  if (tid < nr) {
    int r = tid, ss = 0;
    #pragma unroll
    for (int q = 1; q < NS; q++) if (r >= p8[q]) ss = q;
    int idx = r - p8[ss];
    int slot = gb + r;
    if (idx < 256 && slot < 256) {
      int packed = p.posSlice[(bb * NS + ss) * 256 + idx];
      int d   = packed & 0x3FFF;
      int cls = (packed >> 14) & 31;
      int bi  = (packed >> 19) & 7;
      size_t flat = (size_t)bb * D + d;
      const float4* e4 = (const float4*)(p.line + flat * L);
      float4* o4 = (float4*)(p.emb + slot * L);
      float4* n4 = (float4*)(p.nemb + slot * L);
      float4 v[8];
      float nrm2 = 0.f;
      #pragma unroll
      for (int c = 0; c < 8; c++) {
        v[c] = e4[c];
        o4[c] = v[c];
        nrm2 += v[c].x*v[c].x + v[c].y*v[c].y + v[c].z*v[c].z + v[c].w*v[c].w;
      }
      float inv = 1.f / fmaxf(sqrtf(nrm2), 1e-12f);
      #pragma unroll
      for (int c = 0; c < 8; c++) {
        float4 t = v[c];
        t.x *= inv; t.y *= inv; t.z *= inv; t.w *= inv;
        n4[c] = t;
      }
      p.lab[slot] = cls;
      const float* tr = p.targets + ((size_t)bb * O + bi) * 9;
      p.qp[slot * 3 + 0] = tr[5]; p.qp[slot * 3 + 1] = tr[6]; p.qp[slot * 3 + 2] = tr[7];
    }
  }
  // radix top-k over this batch's mined ce (k = 3*npos)
  const float* ce = p.sce + (size_t)bb * D;
  for (int i = tid; i < D / 4; i += NT)
    ((float4*)sce)[i] = ((const float4*)ce)[i];
  int k = npos * 3; if (k > D) k = D;
  __syncthreads();
  unsigned prefix = 0; int kk = k;            // kk >= 1 (npos >= 1 via forced matches)
  for (int pass = 0; pass < 4; pass++) {
    int shift = 24 - 8 * pass;
    for (int i = tid; i < 16 * 256; i += NT) ((int*)whist)[i] = 0;
    __syncthreads();
    unsigned himask = (pass == 0) ? 0u : (0xFFFFFFFFu << (shift + 8));
    for (int d = tid; d < D; d += NT) {
      unsigned keyb = __float_as_uint(sce[d]);
      if ((keyb & himask) == (prefix & himask))
        atomicAdd(&whist[wav][(keyb >> shift) & 255], 1);
    }
    __syncthreads();
    if (tid < 256) {
      int h = 0;
      #pragma unroll
      for (int w = 0; w < 16; w++) h += whist[w][tid];
      hist[tid] = h;
    }
    __syncthreads();
    if (tid < 64) {
      int l = tid;
      int h0 = hist[l*4], h1 = hist[l*4+1], h2 = hist[l*4+2], h3 = hist[l*4+3];
      int loc4 = h0 + h1 + h2 + h3;
      int suf = loc4;
      #pragma unroll
      for (int st = 1; st < 64; st <<= 1) {
        int o = __shfl_down(suf, st, 64);
        if (l + st < 64) suf += o;
      }
      int snext = suf - loc4;
      int s3 = snext + h3, s2 = s3 + h2, s1 = s2 + h1, s0 = s1 + h0;
      if (s3 >= kk && snext < kk) { prefixSh = prefix | ((unsigned)(l*4+3) << shift); kkSh = kk - snext; }
      if (s2 >= kk && s3 < kk)    { prefixSh = prefix | ((unsigned)(l*4+2) << shift); kkSh = kk - s3; }
      if (s1 >= kk && s2 < kk)    { prefixSh = prefix | ((unsigned)(l*4+1) << shift); kkSh = kk - s2; }
      if (s0 >= kk && s1 < kk)    { prefixSh = prefix | ((unsigned)(l*4+0) << shift); kkSh = kk - s1; }
    }
    __syncthreads();
    prefix = prefixSh; kk = kkSh;
    __syncthreads();
  }
  float T = __uint_as_float(prefix);
  double sgt = 0.0; int cgt = 0;
  for (int d = tid; d < D; d += NT) {
    float v = sce[d];
    if (__float_as_uint(v) > prefix) { sgt += (double)v; cgt++; }
  }
  double wv = waveSumD(sgt);
  double wc = waveSumD((double)cgt);
  if (lane == 0) { wsum[wav] = wv; wcnt2[wav] = wc; }
  __syncthreads();
  if (tid == 0) {
    double tsg = 0, tcg = 0;
    #pragma unroll
    for (int w = 0; w < 16; w++) { tsg += wsum[w]; tcg += wcnt2[w]; }
    p.gCeNeg[bb] = tsg + ((double)k - tcg) * (double)T;
  }
}

// ============ K3: pairs + triplet, block i = row i (256 blocks) ============
__global__ __launch_bounds__(NT) void k_pt2(Ws p) {
  __shared__ float ei[L], ni[L], qi[3];
  __shared__ float sd[256];
  __shared__ unsigned long long spm[4], snm[4];
  __shared__ double w1[4];
  __shared__ int ppc[4], npc[4];
  __shared__ double wS[16], wC[16];
  __shared__ int liS, pcS;
  int i = blockIdx.x, tid = threadIdx.x;
  int lane = tid & 63, wav = tid >> 6;
  int qq = tid >> 8, j = tid & 255;
  if (tid == 0) { pcS = *p.gPc; liS = p.lab[i]; }
  if (tid < L) { ei[tid] = p.emb[i * L + tid]; ni[tid] = p.nemb[i * L + tid]; }
  if (tid >= L && tid < L + 3) qi[tid - L] = p.qp[i * 3 + (tid - L)];
  __syncthreads();
  int Pc = pcS, li = liS;
  bool vi = (i < Pc);
  bool pp = false, np = false;
  double dsk = 0.0;
  if (qq == 0) {
    bool vj = (j < Pc);
    const float4* nj4 = (const float4*)(p.nemb + j * L);
    const float4* ej4 = (const float4*)(p.emb + j * L);
    float sq = 0.f, esq = 0.f;
    #pragma unroll
    for (int c = 0; c < 8; c++) {
      float4 nn = nj4[c], ee = ej4[c];
      float d0 = ni[c*4+0] - nn.x, d1 = ni[c*4+1] - nn.y;
      float d2 = ni[c*4+2] - nn.z, d3 = ni[c*4+3] - nn.w;
      sq += d0*d0 + d1*d1 + d2*d2 + d3*d3;
      float e0 = ei[c*4+0] - ee.x, e1 = ei[c*4+1] - ee.y;
      float e2 = ei[c*4+2] - ee.z, e3 = ei[c*4+3] - ee.w;
      esq += e0*e0 + e1*e1 + e2*e2 + e3*e3;
    }
    float dd = sqrtf(fmaxf(sq, 1e-12f));
    sd[j] = dd;
    float qsq = 0.f;
    #pragma unroll
    for (int c = 0; c < 3; c++) { float dq = qi[c] - p.qp[j * 3 + c]; qsq += dq * dq; }
    bool vp = vi && vj && (i != j);
    bool same = (li == p.lab[j]);
    pp = vp && same && (dd > 0.2f);
    np = vp && !same && (dd < 0.8f);
    float diff = esq - qsq;
    dsk = pp ? (double)diff * (double)diff : 0.0;
  }
  unsigned long long pb = __ballot(pp), nb = __ballot(np);
  double dw = waveSumD(dsk);
  if (lane == 0 && wav < 4) {
    spm[wav] = pb; snm[wav] = nb; w1[wav] = dw;
    ppc[wav] = (int)__popcll(pb); npc[wav] = (int)__popcll(nb);
  }
  __syncthreads();
  unsigned long long pmw = spm[j >> 6];
  bool pj = (pmw >> (j & 63)) & 1ull;
  float sdj = sd[j];
  double ts = 0.0, tc = 0.0;
  if (pj) {
    for (int it = 0; it < 64; it++) {
      int kx = qq + 4 * it;
      unsigned long long nmw = snm[kx >> 6];
      if ((nmw >> (kx & 63)) & 1ull) {
        float x = sdj - sd[kx] + 0.2f;
        if (x > 0.f) { ts += (double)x; tc += 1.0; }
      }
    }
  }
  ts = waveSumD(ts); tc = waveSumD(tc);
  if (lane == 0) { wS[wav] = ts; wC[wav] = tc; }
  __syncthreads();
  if (tid == 0) {
    double S = 0, Cc = 0;
    #pragma unroll
    for (int w = 0; w < 16; w++) { S += wS[w]; Cc += wC[w]; }
    double dsum = w1[0] + w1[1] + w1[2] + w1[3];
    int pcnt = ppc[0] + ppc[1] + ppc[2] + ppc[3];
    int ncnt = npc[0] + npc[1] + npc[2] + npc[3];
    p.gDesk[i] = dsum; p.gNpp[i] = (double)pcnt; p.gNnp[i] = (double)ncnt;
    p.gTripS[i] = S; p.gTripC[i] = Cc;
  }
}

// ============ K4: final reduce (1 block, 256 thr) ============
__global__ __launch_bounds__(256) void k_fin(Ws p) {
  __shared__ double lbuf[4];
  int tid = threadIdx.x;
  auto sumD = [&](const double* a, int n) -> double {
    double v = 0;
    for (int i = tid; i < n; i += 256) v += a[i];
    v = waveSumD(v);
    __syncthreads();
    if ((tid & 63) == 0) lbuf[tid >> 6] = v;
    __syncthreads();
    double r = lbuf[0] + lbuf[1] + lbuf[2] + lbuf[3];
    __syncthreads();
    return r;
  };
  double lossL = sumD(p.gLossL, 256);
  double lossP = sumD(p.gLossP, 256);
  double ceP   = sumD(p.gCeP,   256);
  double ceN   = sumD(p.gCeNeg,  B);
  double desk  = sumD(p.gDesk,  256);
  double npp   = sumD(p.gNpp,   256);
  double nnp   = sumD(p.gNnp,   256);
  double tripS = sumD(p.gTripS, 256);
  double tripC = sumD(p.gTripC, 256);
  double Ntot;
  {
    double v = 0;
    for (int i = tid; i < 256; i += 256) v += (double)p.cnt[i];
    v = waveSumD(v);
    __syncthreads();
    if ((tid & 63) == 0) lbuf[tid >> 6] = v;
    __syncthreads();
    Ntot = lbuf[0] + lbuf[1] + lbuf[2] + lbuf[3];
  }
  if (tid == 0) {
    double N = (Ntot > 0.0) ? Ntot : 1.0;
    p.out[0] = (float)(lossL / N);
    p.out[1] = (float)((ceP + ceN) / N);
    p.out[2] = (float)(lossP / N);
    double cnt = (tripC > 0.0) ? tripC : 1.0;
    double loss_t = tripS / cnt;
    double nppd = (npp > 0.0) ? npp : 1.0;
    double tot = npp + nnp;
    double denom = (tot > 0.0) ? tot : 1.0;
    double Ldesk = desk / nppd + loss_t / denom;
    Ldesk = Ldesk / nppd / 32.0;
    p.out[3] = (float)Ldesk;
    p.out[4] = (float)loss_t;
  }
}

extern "C" void kernel_launch(void* const* d_in, const int* in_sizes, int n_in,
                              void* d_out, int out_size, void* d_ws, size_t ws_size,
                              hipStream_t stream) {
  char* ws = (char*)d_ws;
  size_t off = 0;
  auto alloc = [&](size_t bytes) -> char* {
    char* q = ws + off;
    off += (bytes + 255) & ~(size_t)255;
    return q;
  };
  Ws p;
  p.loc     = (const float*)d_in[0];
  p.conf    = (const float*)d_in[1];
  p.line    = (const float*)d_in[2];
  p.pose    = (const float*)d_in[3];
  p.dbox    = (const float*)d_in[4];
  p.targets = (const float*)d_in[5];
  p.out     = (float*)d_out;
  p.bp       = (unsigned long long*)alloc(B * O * 8);
  p.cnt      = (int*)alloc(256 * 4);
  p.posSlice = (int*)alloc(256 * 256 * 4);
  p.sce      = (float*)alloc((size_t)B * D * 4);
  p.gLossL   = (double*)alloc(256 * 8);
  p.gLossP   = (double*)alloc(256 * 8);
  p.gCeP     = (double*)alloc(256 * 8);
  p.gCeNeg   = (double*)alloc(B * 8);
  p.gDesk    = (double*)alloc(256 * 8);
  p.gNpp     = (double*)alloc(256 * 8);
  p.gNnp     = (double*)alloc(256 * 8);
  p.gTripS   = (double*)alloc(256 * 8);
  p.gTripC   = (double*)alloc(256 * 8);
  p.gPc      = (int*)alloc(256);
  p.emb      = (float*)alloc(256 * L * 4);
  p.nemb     = (float*)alloc(256 * L * 4);
  p.qp       = (float*)alloc(256 * 3 * 4);
  p.lab      = (int*)alloc(256 * 4);

  hipMemsetAsync(p.bp, 0, B * O * 8, stream);
  k_bp   <<<256, 256, 0, stream>>>(p);
  k_slice<<<256, NT, 0, stream>>>(p);
  k_batch<<<B,   NT, 0, stream>>>(p);
  k_pt2  <<<256, NT, 0, stream>>>(p);
  k_fin  <<<1,  256, 0, stream>>>(p);
}